// Round 5
// baseline (205.467 us; speedup 1.0000x reference)
//
#include <hip/hip_runtime.h>
#include <math.h>

// ---------------- constants ----------------
#define KDIM    65536
#define NNODES  100
#define OUTC    60
#define YW      64          // padded col width of Y
#define YSLAB   (NNODES*YW) // 6400 floats per hk

// DMA GEMM chunking: 8 stages of BK=64 -> 512 k per block, grid 768 (3 blk/CU)
#define BK5     64
#define ITERS5  8
#define SLAB5   (BK5*ITERS5)    // 512
#define NKC5    (KDIM/SLAB5)    // 128
// f32 fallback GEMM chunking
#define CHUNK   256
#define NKC     256
#define STEPS   (CHUNK/32)

// ws layout (float offsets)
#define WS_Y    10048       // 6*6400 = 38400 floats
#define WS_E    48448       // end of zero region (E no longer used)
// bf16 x scratch (byte offsets)
#define XB_OFF_BYTES   245760ull
#define XB_BYTES       (100ull*65536ull*2ull)         // 13107200
#define WS_NEED_BYTES  (XB_OFF_BYTES + XB_BYTES)      // 13352960

typedef short bf16x8 __attribute__((ext_vector_type(8)));
typedef float f32x4  __attribute__((ext_vector_type(4)));
typedef unsigned short ushort8 __attribute__((ext_vector_type(8)));

__device__ inline unsigned short f2bf(float f) {
    union { float f; unsigned u; } x; x.f = f;
    unsigned r = x.u + 0x7FFFu + ((x.u >> 16) & 1u);   // RNE (finite inputs)
    return (unsigned short)(r >> 16);
}

// -- pass 1: x f32 -> bf16 stream; also zero Y accumulators and out -------------
__global__ __launch_bounds__(256) void k_cvt_x(const float* __restrict__ x,
                                               ushort8* __restrict__ xb,
                                               float* __restrict__ Y,
                                               float* __restrict__ out) {
    int g = blockIdx.x * 256 + threadIdx.x;
    if (g < 9600) ((f32x4*)Y)[g] = (f32x4){};   // zero 6*6400 floats for atomics
    if (g < 101)  out[g] = 0.f;                 // logits+value accumulate atomically
    for (int i = g; i < 819200; i += 204800) {
        const float4 lo = ((const float4*)x)[2 * i];
        const float4 hi = ((const float4*)x)[2 * i + 1];
        ushort8 o;
        o[0] = f2bf(lo.x); o[1] = f2bf(lo.y); o[2] = f2bf(lo.z); o[3] = f2bf(lo.w);
        o[4] = f2bf(hi.x); o[5] = f2bf(hi.y); o[6] = f2bf(hi.z); o[7] = f2bf(hi.w);
        xb[i] = o;
    }
}

// ---------------- pass 2: GEMM, W direct-to-VGPR, A via LDS DMA ----------------
// 1-D grid 768 (3 blocks/CU -> 12 waves/CU of latency hiding), XCD-swizzled so
// the 6 hk-blocks of one kc share an XCD (A L2 reuse). Block 256 = 4 waves;
// wave = ng (16 cols), 7 m-tiles each. Per stage per wave: 4 A global_load_lds
// + 16 B global_load_dword (reg double-buffered) = exactly 20 ->
// s_waitcnt vmcnt(20) keeps stage t+1 in flight across both barriers.
__global__ __launch_bounds__(256) void k_gemm8(const unsigned short* __restrict__ xb,
                                               const float* __restrict__ wa,
                                               const float* __restrict__ wc,
                                               float* __restrict__ Y) {
    __shared__ unsigned short Ab[2][14 * 512];   // 2 x 14336 B
    __shared__ unsigned short padlds[512];       // 1 KB dummy DMA target
    const int b    = blockIdx.x;
    const int lo8  = b & 7, q = b >> 3;          // q: 0..95
    const int hk   = q % 6;
    const int kc   = lo8 + 8 * (q / 6);          // 0..127; same-kc blocks share XCD
    const int wave = threadIdx.x >> 6;
    const int lane = threadIdx.x & 63;
    const int n16  = lane & 15;
    const int quad = lane >> 4;
    const int c0   = wave * 16;
    const int cidx = min(c0 + n16, OUTC - 1);    // cols 60..63 junk -> Y pad cols
    const int kb0  = kc * SLAB5;

    const float* Wg = (hk < 3 ? wa : wc) + (size_t)(hk % 3) * ((size_t)KDIM * OUTC);

    auto DMA = [&](int buf, int kb) {
#pragma unroll
        for (int j5 = 0; j5 < 4; ++j5) {
            int j = wave + j5 * 4;               // uniform 4 loads/wave
            int chunk = j * 64 + lane;
            int m  = chunk >> 3;
            int cc = (chunk & 7) ^ (m & 7);
            const unsigned short* src =
                xb + (size_t)min(m, NNODES - 1) * KDIM + kb + cc * 8;
            void* dst = (j < 14) ? (void*)&Ab[buf][j * 512] : (void*)padlds;
            __builtin_amdgcn_global_load_lds(
                (const __attribute__((address_space(1))) void*)src,
                (__attribute__((address_space(3))) void*)dst, 16, 0, 0);
        }
    };

    float breg[2][16];                           // static-indexed (full unroll)
    auto LOADB = [&](int pb, int kb) {
        const float* base = Wg + (size_t)(kb + quad * 8) * OUTC + cidx;
#pragma unroll
        for (int s = 0; s < 2; ++s)
#pragma unroll
            for (int j = 0; j < 8; ++j)
                breg[pb][s * 8 + j] = base[(s * 32 + j) * OUTC];
    };

    DMA(0, kb0);
    LOADB(0, kb0);
    f32x4 acc[7] = {};

#pragma unroll
    for (int it = 0; it < ITERS5; ++it) {
        if (it + 1 < ITERS5) {
            DMA((it + 1) & 1, kb0 + (it + 1) * BK5);
            LOADB((it + 1) & 1, kb0 + (it + 1) * BK5);
            asm volatile("s_waitcnt vmcnt(20)" ::: "memory");  // stage t landed
        } else {
            asm volatile("s_waitcnt vmcnt(0)" ::: "memory");
        }
        __builtin_amdgcn_s_barrier();            // buf[it&1] ready for all waves
        const unsigned short* A = Ab[it & 1];
#pragma unroll
        for (int s = 0; s < 2; ++s) {
            bf16x8 bfr;
#pragma unroll
            for (int j = 0; j < 8; ++j)
                bfr[j] = (short)f2bf(breg[it & 1][s * 8 + j]);
            int ch = (s * 4 + quad) ^ (n16 & 7);
#pragma unroll
            for (int t = 0; t < 7; ++t) {
                bf16x8 afr = *(const bf16x8*)(A + (t * 16 + n16) * BK5 + ch * 8);
                acc[t] = __builtin_amdgcn_mfma_f32_16x16x32_bf16(afr, bfr, acc[t], 0, 0, 0);
            }
        }
        __builtin_amdgcn_s_barrier();            // all reads of buf[it&1] done
    }

    // D layout: col = lane&15, row = quad*4 + r within 16x16 tile
    float* Yb = Y + hk * YSLAB;
#pragma unroll
    for (int t = 0; t < 7; ++t)
#pragma unroll
        for (int r = 0; r < 4; ++r) {
            int row = t * 16 + quad * 4 + r;
            if (row < NNODES)
                atomicAdd(&Yb[row * YW + c0 + n16], acc[t][r]);
        }
}

// ---------------- fallback f32 GEMM (used only if ws is too small) -------------
__global__ __launch_bounds__(256, 2) void k_gemm_f32(const float* __restrict__ x,
                                                     const float* __restrict__ wa,
                                                     const float* __restrict__ wc,
                                                     float* __restrict__ Y) {
    const int hk   = blockIdx.x;
    const int kc   = blockIdx.y;
    const int wave = threadIdx.x >> 6;
    const int lane = threadIdx.x & 63;
    const int n16  = lane & 15;
    const int quad = lane >> 4;
    const float* W = (hk < 3 ? wa : wc) + (size_t)(hk % 3) * ((size_t)KDIM * OUTC);
    const int c0   = wave * 16;
    const int cidx = min(c0 + n16, OUTC - 1);
    const int kb0  = kc * CHUNK + quad * 8;
    const float* ap[7];
#pragma unroll
    for (int t = 0; t < 7; ++t)
        ap[t] = x + (size_t)min(n16 + 16 * t, NNODES - 1) * KDIM + kb0;
    const float* bp = W + (size_t)kb0 * OUTC + cidx;
    f32x4 acc[7] = {};
#pragma unroll 2
    for (int s = 0; s < STEPS; ++s) {
        bf16x8 bfr;
        const float* qq = bp + (size_t)s * 32 * OUTC;
#pragma unroll
        for (int j = 0; j < 8; ++j) bfr[j] = (short)f2bf(qq[j * OUTC]);
#pragma unroll
        for (int t = 0; t < 7; ++t) {
            const float* p = ap[t] + s * 32;
            float4 lo = *(const float4*)p;
            float4 hi = *(const float4*)(p + 4);
            bf16x8 afr;
            afr[0] = (short)f2bf(lo.x); afr[1] = (short)f2bf(lo.y);
            afr[2] = (short)f2bf(lo.z); afr[3] = (short)f2bf(lo.w);
            afr[4] = (short)f2bf(hi.x); afr[5] = (short)f2bf(hi.y);
            afr[6] = (short)f2bf(hi.z); afr[7] = (short)f2bf(hi.w);
            acc[t] = __builtin_amdgcn_mfma_f32_16x16x32_bf16(afr, bfr, acc[t], 0, 0, 0);
        }
    }
    float* Yb = Y + hk * YSLAB;
#pragma unroll
    for (int t = 0; t < 7; ++t)
#pragma unroll
        for (int r = 0; r < 4; ++r) {
            int row = t * 16 + quad * 4 + r;
            if (row < NNODES)
                atomicAdd(&Yb[row * YW + c0 + n16], acc[t][r]);
        }
}

// -- kernel 3: build S in LDS + emb = tanh(cheb)+vnr + FUSED head matmuls -------
// grid 120 = (head, c). Each block computes its emb column e[n] (n=0..99) and
// directly accumulates into out: actor blocks do the [100f x 100t] slice of
// flat_a @ actor_fc_w (rows f = n*60+c, coalesced 400B reads), critic blocks
// reduce e . cfw-column to one scalar. Bias folded into the c==0 blocks.
// out must be pre-zeroed (k_cvt_x or memset). E buffer eliminated.
__global__ __launch_bounds__(128) void k_embh(const int* __restrict__ ei,
                                              const float* __restrict__ Y,
                                              const float* __restrict__ vnr,
                                              const float* __restrict__ avw,
                                              const float* __restrict__ avb,
                                              const float* __restrict__ cvw,
                                              const float* __restrict__ cvb,
                                              const float* __restrict__ acb,
                                              const float* __restrict__ ccb,
                                              const float* __restrict__ afcb,
                                              const float* __restrict__ cfcb,
                                              const float* __restrict__ afw,
                                              const float* __restrict__ cfw,
                                              float* __restrict__ out) {
    __shared__ float Sp[NNODES * 101];
    __shared__ float y0[NNODES], y1[NNODES], y2[NNODES], t2[NNODES];
    __shared__ float e[NNODES];
    __shared__ int   deg[NNODES];
    __shared__ float dinv[NNODES];
    const int b = blockIdx.x, head = b / OUTC, c = b % OUTC;
    const int t = threadIdx.x;
    const int* src = ei;
    const int* dst = ei + 1600;

    for (int i = t; i < NNODES * 101; i += 128) Sp[i] = 0.f;
    if (t < NNODES) deg[t] = 0;
    __syncthreads();
    for (int ed = t; ed < 1600; ed += 128) atomicAdd(&deg[src[ed]], 1);
    __syncthreads();
    if (t < NNODES) { int d = deg[t]; dinv[t] = (d > 0) ? rsqrtf((float)d) : 0.f; }
    __syncthreads();
    for (int ed = t; ed < 1600; ed += 128) {
        int s = src[ed], d = dst[ed];
        atomicAdd(&Sp[d * 101 + s], -dinv[s] * dinv[d]);
    }
    const float* Yh = Y + (size_t)head * 3 * YSLAB;
    if (t < NNODES) {
        y0[t] = Yh[t * YW + c];
        y1[t] = Yh[YSLAB + t * YW + c];
        y2[t] = Yh[2 * YSLAB + t * YW + c];
    }
    __syncthreads();

    float z1 = 0.f, s2 = 0.f;
    if (t < NNODES) {
        const float* sr = Sp + t * 101;
        for (int m = 0; m < NNODES; ++m) { z1 += sr[m] * y1[m]; s2 += sr[m] * y2[m]; }
        t2[t] = s2;
    }
    __syncthreads();
    float ev = 0.f;
    if (t < NNODES) {
        const float* sr = Sp + t * 101;
        float t3 = 0.f;
        for (int m = 0; m < NNODES; ++m) t3 += sr[m] * t2[m];
        const float* cb = head ? ccb : acb;
        const float* vw = head ? cvw : avw;
        const float* vb = head ? cvb : avb;
        float u  = y0[t] + z1 + 2.f * t3 - y2[t] + cb[c];
        float vs = vnr[0] * vw[c]        + vb[c]
                 + vnr[1] * vw[OUTC + c] + vb[OUTC + c]
                 + vnr[2] * vw[2*OUTC+c] + vb[2*OUTC+c];
        ev = tanhf(u) + vs;
        e[t] = ev;
    }
    __syncthreads();

    if (head == 0) {
        if (t < NNODES) {                      // logits: thread t owns out[t]
            float s = (c == 0) ? afcb[t] : 0.f;
            const float* wrow = afw + (size_t)c * 100 + t;   // row f=n*60+c
#pragma unroll 4
            for (int n = 0; n < NNODES; ++n) s += e[n] * wrow[(size_t)n * 6000];
            atomicAdd(&out[t], s);
        }
    } else {
        // critic: wave-shuffle reduction of e[t]*cfw[t*60+c] (no LDS atomics)
        float p = (t < NNODES) ? ev * cfw[t * OUTC + c] : 0.f;
#pragma unroll
        for (int off = 32; off > 0; off >>= 1) p += __shfl_down(p, off, 64);
        __shared__ float wsum[2];
        if ((t & 63) == 0) wsum[t >> 6] = p;
        __syncthreads();
        if (t == 0) atomicAdd(&out[100], wsum[0] + wsum[1] + (c == 0 ? cfcb[0] : 0.f));
    }
}

// ---------------- launch ----------------
extern "C" void kernel_launch(void* const* d_in, const int* in_sizes, int n_in,
                              void* d_out, int out_size, void* d_ws, size_t ws_size,
                              hipStream_t stream) {
    const float* x    = (const float*)d_in[0];
    const int*   ei   = (const int*)  d_in[1];
    const float* vnr  = (const float*)d_in[2];
    const float* wa   = (const float*)d_in[3];
    const float* acb  = (const float*)d_in[4];
    const float* wc   = (const float*)d_in[5];
    const float* ccb  = (const float*)d_in[6];
    const float* avw  = (const float*)d_in[7];
    const float* avb  = (const float*)d_in[8];
    const float* cvw  = (const float*)d_in[9];
    const float* cvb  = (const float*)d_in[10];
    const float* afw  = (const float*)d_in[11];
    const float* afcb = (const float*)d_in[12];
    const float* cfw  = (const float*)d_in[13];
    const float* cfcb = (const float*)d_in[14];

    float* ws = (float*)d_ws;
    float* Y  = ws + WS_Y;
    float* out = (float*)d_out;

    if (ws_size >= WS_NEED_BYTES) {
        unsigned short* xb = (unsigned short*)((char*)d_ws + XB_OFF_BYTES);
        k_cvt_x<<<800, 256, 0, stream>>>(x, (ushort8*)xb, Y, out); // zeroes Y+out
        k_gemm8<<<768, 256, 0, stream>>>(xb, wa, wc, Y);
    } else {
        hipMemsetAsync((char*)d_ws + WS_Y * 4, 0, (WS_E - WS_Y) * 4, stream);
        hipMemsetAsync(d_out, 0, 101 * sizeof(float), stream);
        k_gemm_f32<<<dim3(6, NKC), 256, 0, stream>>>(x, wa, wc, Y);
    }

    k_embh<<<120, 128, 0, stream>>>(ei, Y, vnr, avw, avb, cvw, cvb,
                                    acb, ccb, afcb, cfcb, afw, cfw, out);
}